// Round 1
// baseline (255.759 us; speedup 1.0000x reference)
//
#include <hip/hip_runtime.h>
#include <cstdint>
#include <cstddef>

// ---- problem constants ----
#define DIMC    192
#define NHEADS  6
#define HEADD   32
#define KWIN    3
#define KK2     9      // K*K
#define NATT    486    // HEADS*KK*KK
#define NB      16
#define NH      56
#define NWW     56
#define HPOOL   28
#define WPOOL   28
#define NPIX    784    // 28*28
#define VH      58     // padded
#define VW      58
#define MROWS   (NB*NH*NWW)      // 50176
#define SCALE_A 0.17677669529663687f   // 32^-0.5

// =====================================================================
// GEMM: C[M x 192] = A[M x 192] * W[192 x 192]  (+ bias)
// MODE 0: scatter result into padded vp layout (16,58,58,192), no bias
// MODE 1: plain row-major output with bias
// Block: 256 threads, 64x64 output tile, 4x4 per thread, BK=16.
// =====================================================================
template<int MODE>
__global__ __launch_bounds__(256)
void gemm192_kernel(const float* __restrict__ A, const float* __restrict__ W,
                    const float* __restrict__ bias, float* __restrict__ C)
{
    __shared__ float As[16][68];   // [k][m], padded stride 68 (16B-mult, kills 4-way store conflict)
    __shared__ float Bs[16][64];   // [k][n]

    const int t  = threadIdx.x;
    const int ty = t >> 4;         // 0..15 -> row group
    const int tx = t & 15;         // 0..15 -> col group
    const int by = blockIdx.y;     // 0..783
    const int bx = blockIdx.x;     // 0..2

    const int arow = t >> 2;          // 0..63
    const int acol = (t & 3) << 2;    // 0,4,8,12
    const int brow = t >> 4;          // 0..15
    const int bcol = (t & 15) << 2;   // 0..60

    float acc[4][4];
#pragma unroll
    for (int i = 0; i < 4; ++i)
#pragma unroll
        for (int j = 0; j < 4; ++j) acc[i][j] = 0.f;

    const float* Aptr = A + (size_t)(by * 64 + arow) * DIMC + acol;
    const float* Wptr = W + (size_t)brow * DIMC + bx * 64 + bcol;

    for (int kk = 0; kk < DIMC; kk += 16) {
        float4 av = *(const float4*)(Aptr + kk);
        float4 bv = *(const float4*)(Wptr + (size_t)kk * DIMC);
        __syncthreads();
        As[acol + 0][arow] = av.x;
        As[acol + 1][arow] = av.y;
        As[acol + 2][arow] = av.z;
        As[acol + 3][arow] = av.w;
        *(float4*)&Bs[brow][bcol] = bv;
        __syncthreads();
#pragma unroll
        for (int k = 0; k < 16; ++k) {
            float4 a4 = *(const float4*)&As[k][ty << 2];
            float4 b4 = *(const float4*)&Bs[k][tx << 2];
            acc[0][0] = fmaf(a4.x, b4.x, acc[0][0]);
            acc[0][1] = fmaf(a4.x, b4.y, acc[0][1]);
            acc[0][2] = fmaf(a4.x, b4.z, acc[0][2]);
            acc[0][3] = fmaf(a4.x, b4.w, acc[0][3]);
            acc[1][0] = fmaf(a4.y, b4.x, acc[1][0]);
            acc[1][1] = fmaf(a4.y, b4.y, acc[1][1]);
            acc[1][2] = fmaf(a4.y, b4.z, acc[1][2]);
            acc[1][3] = fmaf(a4.y, b4.w, acc[1][3]);
            acc[2][0] = fmaf(a4.z, b4.x, acc[2][0]);
            acc[2][1] = fmaf(a4.z, b4.y, acc[2][1]);
            acc[2][2] = fmaf(a4.z, b4.z, acc[2][2]);
            acc[2][3] = fmaf(a4.z, b4.w, acc[2][3]);
            acc[3][0] = fmaf(a4.w, b4.x, acc[3][0]);
            acc[3][1] = fmaf(a4.w, b4.y, acc[3][1]);
            acc[3][2] = fmaf(a4.w, b4.z, acc[3][2]);
            acc[3][3] = fmaf(a4.w, b4.w, acc[3][3]);
        }
    }

    const int col = bx * 64 + (tx << 2);
    if (MODE == 1) {
        float4 bv = *(const float4*)&bias[col];
#pragma unroll
        for (int i = 0; i < 4; ++i) {
            int m = by * 64 + (ty << 2) + i;
            float4 v = make_float4(acc[i][0] + bv.x, acc[i][1] + bv.y,
                                   acc[i][2] + bv.z, acc[i][3] + bv.w);
            *(float4*)&C[(size_t)m * DIMC + col] = v;
        }
    } else {
#pragma unroll
        for (int i = 0; i < 4; ++i) {
            int m  = by * 64 + (ty << 2) + i;
            int b  = m / (NH * NWW);
            int r  = m - b * (NH * NWW);
            int hi = r / NWW;
            int wi = r - hi * NWW;
            float4 v = make_float4(acc[i][0], acc[i][1], acc[i][2], acc[i][3]);
            *(float4*)&C[(((size_t)b * VH + hi + 1) * VW + (wi + 1)) * DIMC + col] = v;
        }
    }
}

// =====================================================================
// Pool (2x2 avg) + attention GEMM (pooled @ Wa + ba) + softmax
// One block = 8 pooled pixels (same batch). 256 threads.
// =====================================================================
__global__ __launch_bounds__(256)
void pool_attn_kernel(const float* __restrict__ x, const float* __restrict__ Wa,
                      const float* __restrict__ ba, float* __restrict__ attn)
{
    __shared__ float pool_s[8][DIMC];
    __shared__ float a_s[8][NATT + 2];

    const int t  = threadIdx.x;
    const int blk = blockIdx.x;
    const int b  = blk / 98;
    const int n0 = (blk - b * 98) * 8;

    // ---- 2x2 average pool into LDS ----
    for (int idx = t; idx < 8 * DIMC; idx += 256) {
        int pi = idx / DIMC;
        int c  = idx - pi * DIMC;
        int n  = n0 + pi;
        int hh = n / WPOOL;
        int ww = n - hh * WPOOL;
        const float* xp = x + (((size_t)(b * NH + hh * 2)) * NWW + ww * 2) * DIMC + c;
        float s = xp[0] + xp[DIMC] + xp[(size_t)NWW * DIMC] + xp[(size_t)NWW * DIMC + DIMC];
        pool_s[pi][c] = 0.25f * s;
    }
    __syncthreads();

    // ---- pooled @ Wa + ba  (486 cols; thread t<243 does cols t, t+243) ----
    if (t < 243) {
        float acc0[8], acc1[8];
#pragma unroll
        for (int pi = 0; pi < 8; ++pi) { acc0[pi] = 0.f; acc1[pi] = 0.f; }
        for (int k = 0; k < DIMC; ++k) {
            float w0 = Wa[(size_t)k * NATT + t];
            float w1 = Wa[(size_t)k * NATT + t + 243];
#pragma unroll
            for (int pi = 0; pi < 8; ++pi) {
                float p = pool_s[pi][k];
                acc0[pi] = fmaf(p, w0, acc0[pi]);
                acc1[pi] = fmaf(p, w1, acc1[pi]);
            }
        }
        float b0 = ba[t], b1 = ba[t + 243];
#pragma unroll
        for (int pi = 0; pi < 8; ++pi) {
            a_s[pi][t]       = (acc0[pi] + b0) * SCALE_A;
            a_s[pi][t + 243] = (acc1[pi] + b1) * SCALE_A;
        }
    }
    __syncthreads();

    // ---- softmax over q (rows of 9), 8*6*9 = 432 rows ----
    for (int row = t; row < 432; row += 256) {
        int pi   = row / 54;
        int rem  = row - pi * 54;
        int head = rem / 9;
        int pp   = rem - head * 9;
        const float* ap = &a_s[pi][head * 81 + pp * 9];
        float m = ap[0];
#pragma unroll
        for (int q = 1; q < 9; ++q) m = fmaxf(m, ap[q]);
        float e[9];
        float sum = 0.f;
#pragma unroll
        for (int q = 0; q < 9; ++q) { e[q] = __expf(ap[q] - m); sum += e[q]; }
        float inv = 1.f / sum;
        int n = n0 + pi;
        float* dst = attn + (((size_t)(b * NPIX + n) * NHEADS + head) * 81 + pp * 9);
#pragma unroll
        for (int q = 0; q < 9; ++q) dst[q] = e[q] * inv;
    }
}

// =====================================================================
// Gather: y[b,p,qc,c] = sum over valid (i,j) and q of
//         attn[b, n(hh,ww), head, i*3+j, q] * vp[b, (p+1-i)+qi, (qc+1-j)+qj, c]
// One block per output pixel, 192 threads (thread = channel).
// =====================================================================
__global__ __launch_bounds__(192)
void outlook_gather_kernel(const float* __restrict__ attn, const float* __restrict__ vp,
                           float* __restrict__ y)
{
    const int blk = blockIdx.x;           // b*3136 + p*56 + qc
    const int c   = threadIdx.x;
    const int b   = blk / (NH * NWW);
    const int rem = blk - b * (NH * NWW);
    const int p   = rem / NWW;
    const int qc  = rem - (rem / NWW) * NWW;
    const int head = c >> 5;

    float acc = 0.f;
#pragma unroll
    for (int i = 0; i < 3; ++i) {
        int th = p + 1 - i;                       // = 2*hh if valid
        if ((th & 1) || (th >> 1) >= HPOOL || th < 0) continue;
        int hh = th >> 1;
#pragma unroll
        for (int j = 0; j < 3; ++j) {
            int tw = qc + 1 - j;
            if ((tw & 1) || (tw >> 1) >= WPOOL || tw < 0) continue;
            int ww = tw >> 1;
            const float* ap = attn +
                (((size_t)(b * NPIX + hh * WPOOL + ww) * NHEADS + head) * 81 + (i * 3 + j) * 9);
            const float* vpp = vp + (((size_t)(b * VH + th)) * VW + tw) * DIMC + c;
#pragma unroll
            for (int qi = 0; qi < 3; ++qi)
#pragma unroll
                for (int qj = 0; qj < 3; ++qj) {
                    acc = fmaf(ap[qi * 3 + qj], vpp[((size_t)qi * VW + qj) * DIMC], acc);
                }
        }
    }
    y[(size_t)blk * DIMC + c] = acc;
}

// =====================================================================
extern "C" void kernel_launch(void* const* d_in, const int* in_sizes, int n_in,
                              void* d_out, int out_size, void* d_ws, size_t ws_size,
                              hipStream_t stream)
{
    const float* x  = (const float*)d_in[0];
    const float* Wv = (const float*)d_in[1];
    const float* Wa = (const float*)d_in[2];
    const float* ba = (const float*)d_in[3];
    const float* Wp = (const float*)d_in[4];
    const float* bp = (const float*)d_in[5];
    float* out = (float*)d_out;

    const size_t vp_elems   = (size_t)NB * VH * VW * DIMC;       // 10,334,208
    const size_t attn_elems = (size_t)NB * NPIX * NATT;          //  6,096,384
    float* vp   = (float*)d_ws;
    float* attn = vp + vp_elems;
    float* y    = attn + attn_elems;

    // zero vp (borders must be 0; interior overwritten by GEMM)
    hipMemsetAsync(vp, 0, vp_elems * sizeof(float), stream);

    // v = x @ Wv, scattered into padded layout
    gemm192_kernel<0><<<dim3(3, MROWS / 64), 256, 0, stream>>>(x, Wv, nullptr, vp);

    // pooled + attention logits + softmax
    pool_attn_kernel<<<dim3(NB * 98), 256, 0, stream>>>(x, Wa, ba, attn);

    // einsum + fold (gather form)
    outlook_gather_kernel<<<dim3(NB * NH * NWW), 192, 0, stream>>>(attn, vp, y);

    // out = y @ Wp + bp
    gemm192_kernel<1><<<dim3(3, MROWS / 64), 256, 0, stream>>>(y, Wp, bp, out);
}

// Round 2
// 188.570 us; speedup vs baseline: 1.3563x; 1.3563x over previous
//
#include <hip/hip_runtime.h>
#include <cstdint>
#include <cstddef>

// ---- problem constants ----
#define DIMC    192
#define NHEADS  6
#define HEADD   32
#define KWIN    3
#define KK2     9
#define NATT    486
#define NB      16
#define NH      56
#define NWW     56
#define HPOOL   28
#define WPOOL   28
#define NPIX    784
#define VH      58
#define VW      58
#define MROWS   (NB*NH*NWW)      // 50176
#define SCALE_A 0.17677669529663687f

using bf16x8 = __attribute__((ext_vector_type(8))) short;
using f32x4  = __attribute__((ext_vector_type(4))) float;

static __device__ __forceinline__ unsigned short f2bf(float f) {
    unsigned int u = __float_as_uint(f);
    unsigned int r = (u + 0x7fffu + ((u >> 16) & 1u)) >> 16;   // RNE
    return (unsigned short)r;
}

// =====================================================================
// WT[n][k] = bf16(W[k][n]) for Wv and Wp (tiny, 73728 elems total)
// =====================================================================
__global__ __launch_bounds__(256)
void wt_convert_kernel(const float* __restrict__ Wv, const float* __restrict__ Wp,
                       unsigned short* __restrict__ WTv, unsigned short* __restrict__ WTp)
{
    int idx = blockIdx.x * 256 + threadIdx.x;        // 0..73727
    int sel = idx / 36864;
    int r   = idx - sel * 36864;
    int n   = r / DIMC;
    int k   = r - n * DIMC;
    const float* W = sel ? Wp : Wv;
    unsigned short* WT = sel ? WTp : WTv;
    WT[r] = f2bf(W[k * DIMC + n]);
}

// =====================================================================
// Zero only the 1-pixel border of vp (interior fully written by GEMM0)
// 16 * 228 * 192 = 700416 elements
// =====================================================================
__global__ __launch_bounds__(256)
void vp_border_zero_kernel(float* __restrict__ vp)
{
    int idx  = blockIdx.x * 256 + threadIdx.x;
    int c    = idx % DIMC;
    int rest = idx / DIMC;          // 0..3647
    int b    = rest / 228;
    int p    = rest - b * 228;
    int hi, wi;
    if (p < 58)       { hi = 0;  wi = p; }
    else if (p < 116) { hi = 57; wi = p - 58; }
    else { int q = p - 116; hi = 1 + (q >> 1); wi = (q & 1) * 57; }
    vp[(((size_t)b * VH + hi) * VW + wi) * DIMC + c] = 0.f;
}

// =====================================================================
// MFMA GEMM: C[M x 192] = A[M x 192] (fp32) * WT^T (bf16 WT[n][k]) (+bias)
// Block: 256 thr (4 waves, 2x2), BM=64, BN=192 (full N), K=192 staged whole.
// MODE 0: scatter into padded vp layout; MODE 1: row-major + bias.
// A staged to LDS as bf16, XOR-swizzled (byte ^= (row&7)<<4) so the
// stride-384B ds_read_b128 column reads are <=2-way (free, m136).
// =====================================================================
template<int MODE>
__global__ __launch_bounds__(256)
void mfma_gemm_kernel(const float* __restrict__ A, const unsigned short* __restrict__ WT,
                      const float* __restrict__ bias, float* __restrict__ C)
{
    __shared__ unsigned short As[64 * DIMC];   // 24 KB, swizzled bf16

    const int t  = threadIdx.x;
    const int l  = t & 63;
    const int w  = t >> 6;
    const int wr = w >> 1;          // 0..1 : row half
    const int wc = w & 1;           // 0..1 : col half (96 each)
    const int by = blockIdx.x;      // 0..783

    // ---- stage A tile (64 rows x 192 k), fp32 -> bf16, swizzled ----
    const float* Ab = A + (size_t)by * 64 * DIMC;
#pragma unroll
    for (int i = 0; i < 12; ++i) {
        int f = i * 1024 + t * 4;                 // flat idx, coalesced float4
        float4 v = *(const float4*)(Ab + f);
        int row = f / DIMC;
        int k   = f - row * DIMC;
        ushort4 u;
        u.x = f2bf(v.x); u.y = f2bf(v.y); u.z = f2bf(v.z); u.w = f2bf(v.w);
        int off = (row * 384 + k * 2) ^ ((row & 7) << 4);
        *(ushort4*)((char*)As + off) = u;
    }
    __syncthreads();

    f32x4 acc[2][6];
#pragma unroll
    for (int mi = 0; mi < 2; ++mi)
#pragma unroll
        for (int ni = 0; ni < 6; ++ni) acc[mi][ni] = (f32x4)0.f;

    const int arow0 = wr * 32 + (l & 15);
    const int kb    = (l >> 4) << 4;    // byte offset of lane's k-group within 64B step

#pragma unroll
    for (int ks = 0; ks < 6; ++ks) {
        bf16x8 a[2], b[6];
#pragma unroll
        for (int mi = 0; mi < 2; ++mi) {
            int row = arow0 + mi * 16;
            int off = (row * 384 + ks * 64 + kb) ^ ((row & 7) << 4);
            a[mi] = *(const bf16x8*)((const char*)As + off);
        }
#pragma unroll
        for (int ni = 0; ni < 6; ++ni) {
            int n = wc * 96 + ni * 16 + (l & 15);
            b[ni] = *(const bf16x8*)(WT + (size_t)n * DIMC + ks * 32 + ((l >> 4) << 3));
        }
#pragma unroll
        for (int mi = 0; mi < 2; ++mi)
#pragma unroll
            for (int ni = 0; ni < 6; ++ni)
                acc[mi][ni] = __builtin_amdgcn_mfma_f32_16x16x32_bf16(
                    a[mi], b[ni], acc[mi][ni], 0, 0, 0);
    }

    // ---- epilogue: C/D layout col = l&15, row = (l>>4)*4 + r (m89) ----
#pragma unroll
    for (int mi = 0; mi < 2; ++mi) {
#pragma unroll
        for (int r = 0; r < 4; ++r) {
            int m = by * 64 + wr * 32 + mi * 16 + ((l >> 4) << 2) + r;
            float* dst;
            if (MODE == 1) {
                dst = C + (size_t)m * DIMC;
            } else {
                int bb = m / (NH * NWW);
                int rr = m - bb * (NH * NWW);
                int hi = rr / NWW;
                int wi = rr - hi * NWW;
                dst = C + (((size_t)bb * VH + hi + 1) * VW + (wi + 1)) * DIMC;
            }
#pragma unroll
            for (int ni = 0; ni < 6; ++ni) {
                int col = wc * 96 + ni * 16 + (l & 15);
                float v = acc[mi][ni][r];
                if (MODE == 1) v += bias[col];
                dst[col] = v;
            }
        }
    }
}

// =====================================================================
// Pool (2x2 avg) + attention GEMM (pooled @ Wa + ba) + softmax
// =====================================================================
__global__ __launch_bounds__(256)
void pool_attn_kernel(const float* __restrict__ x, const float* __restrict__ Wa,
                      const float* __restrict__ ba, float* __restrict__ attn)
{
    __shared__ float pool_s[8][DIMC];
    __shared__ float a_s[8][NATT + 2];

    const int t  = threadIdx.x;
    const int blk = blockIdx.x;
    const int b  = blk / 98;
    const int n0 = (blk - b * 98) * 8;

    for (int idx = t; idx < 8 * DIMC; idx += 256) {
        int pi = idx / DIMC;
        int c  = idx - pi * DIMC;
        int n  = n0 + pi;
        int hh = n / WPOOL;
        int ww = n - hh * WPOOL;
        const float* xp = x + (((size_t)(b * NH + hh * 2)) * NWW + ww * 2) * DIMC + c;
        float s = xp[0] + xp[DIMC] + xp[(size_t)NWW * DIMC] + xp[(size_t)NWW * DIMC + DIMC];
        pool_s[pi][c] = 0.25f * s;
    }
    __syncthreads();

    if (t < 243) {
        float acc0[8], acc1[8];
#pragma unroll
        for (int pi = 0; pi < 8; ++pi) { acc0[pi] = 0.f; acc1[pi] = 0.f; }
        for (int k = 0; k < DIMC; ++k) {
            float w0 = Wa[(size_t)k * NATT + t];
            float w1 = Wa[(size_t)k * NATT + t + 243];
#pragma unroll
            for (int pi = 0; pi < 8; ++pi) {
                float p = pool_s[pi][k];
                acc0[pi] = fmaf(p, w0, acc0[pi]);
                acc1[pi] = fmaf(p, w1, acc1[pi]);
            }
        }
        float b0 = ba[t], b1 = ba[t + 243];
#pragma unroll
        for (int pi = 0; pi < 8; ++pi) {
            a_s[pi][t]       = (acc0[pi] + b0) * SCALE_A;
            a_s[pi][t + 243] = (acc1[pi] + b1) * SCALE_A;
        }
    }
    __syncthreads();

    for (int row = t; row < 432; row += 256) {
        int pi   = row / 54;
        int rem  = row - pi * 54;
        int head = rem / 9;
        int pp   = rem - head * 9;
        const float* ap = &a_s[pi][head * 81 + pp * 9];
        float m = ap[0];
#pragma unroll
        for (int q = 1; q < 9; ++q) m = fmaxf(m, ap[q]);
        float e[9];
        float sum = 0.f;
#pragma unroll
        for (int q = 0; q < 9; ++q) { e[q] = __expf(ap[q] - m); sum += e[q]; }
        float inv = 1.f / sum;
        int n = n0 + pi;
        float* dst = attn + (((size_t)(b * NPIX + n) * NHEADS + head) * 81 + pp * 9);
#pragma unroll
        for (int q = 0; q < 9; ++q) dst[q] = e[q] * inv;
    }
}

// =====================================================================
// Gather: y[b,p,qc,c] (unchanged from R1)
// =====================================================================
__global__ __launch_bounds__(192)
void outlook_gather_kernel(const float* __restrict__ attn, const float* __restrict__ vp,
                           float* __restrict__ y)
{
    const int blk = blockIdx.x;
    const int c   = threadIdx.x;
    const int b   = blk / (NH * NWW);
    const int rem = blk - b * (NH * NWW);
    const int p   = rem / NWW;
    const int qc  = rem - (rem / NWW) * NWW;
    const int head = c >> 5;

    float acc = 0.f;
#pragma unroll
    for (int i = 0; i < 3; ++i) {
        int th = p + 1 - i;
        if ((th & 1) || (th >> 1) >= HPOOL || th < 0) continue;
        int hh = th >> 1;
#pragma unroll
        for (int j = 0; j < 3; ++j) {
            int tw = qc + 1 - j;
            if ((tw & 1) || (tw >> 1) >= WPOOL || tw < 0) continue;
            int ww = tw >> 1;
            const float* ap = attn +
                (((size_t)(b * NPIX + hh * WPOOL + ww) * NHEADS + head) * 81 + (i * 3 + j) * 9);
            const float* vpp = vp + (((size_t)(b * VH + th)) * VW + tw) * DIMC + c;
#pragma unroll
            for (int qi = 0; qi < 3; ++qi)
#pragma unroll
                for (int qj = 0; qj < 3; ++qj) {
                    acc = fmaf(ap[qi * 3 + qj], vpp[((size_t)qi * VW + qj) * DIMC], acc);
                }
        }
    }
    y[(size_t)blk * DIMC + c] = acc;
}

// =====================================================================
extern "C" void kernel_launch(void* const* d_in, const int* in_sizes, int n_in,
                              void* d_out, int out_size, void* d_ws, size_t ws_size,
                              hipStream_t stream)
{
    const float* x  = (const float*)d_in[0];
    const float* Wv = (const float*)d_in[1];
    const float* Wa = (const float*)d_in[2];
    const float* ba = (const float*)d_in[3];
    const float* Wp = (const float*)d_in[4];
    const float* bp = (const float*)d_in[5];
    float* out = (float*)d_out;

    const size_t vp_elems   = (size_t)NB * VH * VW * DIMC;   // 10,334,208
    const size_t attn_elems = (size_t)NB * NPIX * NATT;      //  6,096,384
    const size_t y_elems    = (size_t)MROWS * DIMC;          //  9,633,792
    float* vp   = (float*)d_ws;
    float* attn = vp + vp_elems;
    float* y    = attn + attn_elems;
    unsigned short* WTv = (unsigned short*)(y + y_elems);
    unsigned short* WTp = WTv + 36864;

    // border of vp must be 0; interior fully overwritten by GEMM0
    vp_border_zero_kernel<<<2736, 256, 0, stream>>>(vp);

    // W -> bf16 transposed [n][k]
    wt_convert_kernel<<<288, 256, 0, stream>>>(Wv, Wp, WTv, WTp);

    // v = x @ Wv -> padded vp (bf16 MFMA)
    mfma_gemm_kernel<0><<<MROWS / 64, 256, 0, stream>>>(x, WTv, nullptr, vp);

    // pooled + attention logits + softmax
    pool_attn_kernel<<<NB * 98, 256, 0, stream>>>(x, Wa, ba, attn);

    // einsum + fold (gather form)
    outlook_gather_kernel<<<NB * NH * NWW, 192, 0, stream>>>(attn, vp, y);

    // out = y @ Wp + bp (bf16 MFMA)
    mfma_gemm_kernel<1><<<MROWS / 64, 256, 0, stream>>>(y, WTp, bp, out);
}